// Round 3
// baseline (67.671 us; speedup 1.0000x reference)
//
#include <hip/hip_runtime.h>
#include <math.h>

#define BB 32
#define NN 4096
#define DD 512
#define CC 5

// DPP-add step: v += dpp_permuted(v). 0 for lanes with no source (bound_ctrl).
#define DPP_ADD(v, ctrl, rmask)                                                 \
    (v) += __int_as_float(__builtin_amdgcn_update_dpp(                          \
        0, __float_as_int(v), (ctrl), (rmask), 0xF, true))

// Canonical CDNA wave64 all-reduce via DPP only (no DS pipe):
// row_shr 1/2/4/8 (intra-row inclusive prefix), row_bcast15 (rows 1,3),
// row_bcast31 (rows 2,3) -> lane 63 holds the full sum; readlane 63 gives a
// wave-uniform (SGPR) result.
static __device__ __forceinline__ float wave_allreduce_add(float v)
{
    DPP_ADD(v, 0x111, 0xF);   // row_shr:1
    DPP_ADD(v, 0x112, 0xF);   // row_shr:2
    DPP_ADD(v, 0x114, 0xF);   // row_shr:4
    DPP_ADD(v, 0x118, 0xF);   // row_shr:8
    DPP_ADD(v, 0x142, 0xA);   // row_bcast:15 -> rows 1,3
    DPP_ADD(v, 0x143, 0xC);   // row_bcast:31 -> rows 2,3
    return __int_as_float(__builtin_amdgcn_readlane(__float_as_int(v), 63));
}

// Pass 1: stream x once. Each block = (b, segment of N). 4 waves per block,
// each wave processes rows round-robin with an online-softmax weighted
// accumulator. e/m/l are wave-uniform scalars (SGPR); only acc/W/x use VGPRs.
__global__ __launch_bounds__(256, 4)
void capsule_pass1(const float* __restrict__ x, const float* __restrict__ Wa,
                   float* __restrict__ acc_ws, float* __restrict__ ml_ws,
                   int S, int rows_per_seg)
{
    const int blk  = blockIdx.x;
    const int b    = blk / S;
    const int seg  = blk % S;
    const int tid  = threadIdx.x;
    const int lane = tid & 63;
    const int wid  = tid >> 6;   // 0..3

    // lane owns d in [d0, d0+4) and [d1, d1+4)
    const int d0 = lane * 4;
    const int d1 = 256 + lane * 4;

    // W_alpha fragments: 20 contiguous floats per half (4 d's x 5 c's),
    // loaded as 5 float4 each. Indexed wa[j*5+c], all compile-time indices.
    float wal[20], wah[20];
    {
        const float4* pl = reinterpret_cast<const float4*>(Wa + d0 * CC);
        const float4* ph = reinterpret_cast<const float4*>(Wa + d1 * CC);
#pragma unroll
        for (int q = 0; q < 5; ++q) {
            float4 a = pl[q];
            wal[q * 4 + 0] = a.x; wal[q * 4 + 1] = a.y;
            wal[q * 4 + 2] = a.z; wal[q * 4 + 3] = a.w;
            float4 b4 = ph[q];
            wah[q * 4 + 0] = b4.x; wah[q * 4 + 1] = b4.y;
            wah[q * 4 + 2] = b4.z; wah[q * 4 + 3] = b4.w;
        }
    }

    float acc[CC][8];
    float m[CC], l[CC];   // wave-uniform -> SGPR
#pragma unroll
    for (int c = 0; c < CC; ++c) {
        m[c] = -INFINITY;
        l[c] = 0.0f;
#pragma unroll
        for (int j = 0; j < 8; ++j) acc[c][j] = 0.0f;
    }

    const float* xseg = x + ((size_t)b * NN + (size_t)seg * rows_per_seg) * DD;

    // depth-1 software prefetch (clamped pointer: last iter re-loads current)
    float4 na = *reinterpret_cast<const float4*>(xseg + (size_t)wid * DD + d0);
    float4 nb = *reinterpret_cast<const float4*>(xseg + (size_t)wid * DD + d1);

    for (int i = wid; i < rows_per_seg; i += 4) {
        const float4 xa = na;
        const float4 xb = nb;
        const int nx = (i + 4 < rows_per_seg) ? (i + 4) : i;
        const float* nxr = xseg + (size_t)nx * DD;
        na = *reinterpret_cast<const float4*>(nxr + d0);
        nb = *reinterpret_cast<const float4*>(nxr + d1);

        const float xv[8] = {xa.x, xa.y, xa.z, xa.w, xb.x, xb.y, xb.z, xb.w};

        float e[CC];
#pragma unroll
        for (int c = 0; c < CC; ++c) {
            float s = 0.0f;
#pragma unroll
            for (int j = 0; j < 4; ++j) s = fmaf(xv[j], wal[j * CC + c], s);
#pragma unroll
            for (int j = 0; j < 4; ++j) s = fmaf(xv[4 + j], wah[j * CC + c], s);
            e[c] = wave_allreduce_add(s);   // wave-uniform
        }

        // online softmax-weighted accumulation (scalar branch per capsule)
#pragma unroll
        for (int c = 0; c < CC; ++c) {
            if (e[c] > m[c]) {
                const float s = __expf(m[c] - e[c]);   // 0 when m == -inf
                l[c] = l[c] * s + 1.0f;
#pragma unroll
                for (int j = 0; j < 8; ++j) acc[c][j] = fmaf(acc[c][j], s, xv[j]);
                m[c] = e[c];
            } else {
                const float pe = __expf(e[c] - m[c]);
                l[c] += pe;
#pragma unroll
                for (int j = 0; j < 8; ++j) acc[c][j] = fmaf(pe, xv[j], acc[c][j]);
            }
        }
    }

    // ---- combine the 4 waves ----
    __shared__ float s_ml[4][CC][2];
    __shared__ float s_acc[CC][DD];   // 10 KB

    if (lane == 0) {
#pragma unroll
        for (int c = 0; c < CC; ++c) {
            s_ml[wid][c][0] = m[c];
            s_ml[wid][c][1] = l[c];
        }
    }
    __syncthreads();

    float mb[CC], lb[CC], cw[CC];
#pragma unroll
    for (int c = 0; c < CC; ++c) {
        float mm = s_ml[0][c][0];
#pragma unroll
        for (int w = 1; w < 4; ++w) mm = fmaxf(mm, s_ml[w][c][0]);
        mb[c] = mm;
        float ll = 0.0f;
#pragma unroll
        for (int w = 0; w < 4; ++w) ll += __expf(s_ml[w][c][0] - mm) * s_ml[w][c][1];
        lb[c] = ll;
        cw[c] = __expf(s_ml[wid][c][0] - mm);   // this wave's rescale coeff
    }

    // waves deposit (rescaled) accumulators into LDS sequentially
    for (int w = 0; w < 4; ++w) {
        if (wid == w) {
#pragma unroll
            for (int c = 0; c < CC; ++c) {
#pragma unroll
                for (int j = 0; j < 8; ++j) {
                    const int d = (j < 4) ? (d0 + j) : (d1 + j - 4);
                    const float v = acc[c][j] * cw[c];
                    if (w == 0) s_acc[c][d] = v;
                    else        s_acc[c][d] += v;
                }
            }
        }
        __syncthreads();
    }

    // write block partials to workspace (float4)
    float4* accp = reinterpret_cast<float4*>(acc_ws + (size_t)blk * CC * DD);
    const float4* sa = reinterpret_cast<const float4*>(&s_acc[0][0]);
    for (int idx = tid; idx < CC * DD / 4; idx += 256) accp[idx] = sa[idx];
    if (tid < CC) {
        ml_ws[((size_t)blk * CC + tid) * 2 + 0] = mb[tid];
        ml_ws[((size_t)blk * CC + tid) * 2 + 1] = lb[tid];
    }
}

// Pass 2: one block per (b,c). Combine S segment partials, normalize,
// epilogue p = tanh(v.w + b), r = p*v, write all three outputs.
__global__ __launch_bounds__(256)
void capsule_pass2(const float* __restrict__ acc_ws, const float* __restrict__ ml_ws,
                   const float* __restrict__ lin_w, const float* __restrict__ lin_b,
                   float* __restrict__ p_out, float* __restrict__ v_out,
                   float* __restrict__ r_out, int S)
{
    const int bc  = blockIdx.x;          // 0..B*C-1
    const int b   = bc / CC;
    const int c   = bc % CC;
    const int tid = threadIdx.x;

    __shared__ float s_w[64];
    __shared__ float s_red[4];
    __shared__ float s_p;

    float mg = -INFINITY;
    for (int s = 0; s < S; ++s)
        mg = fmaxf(mg, ml_ws[(((size_t)b * S + s) * CC + c) * 2]);
    float lg = 0.0f;
    for (int s = 0; s < S; ++s) {
        const float mw = ml_ws[(((size_t)b * S + s) * CC + c) * 2];
        const float lw = ml_ws[(((size_t)b * S + s) * CC + c) * 2 + 1];
        const float w  = __expf(mw - mg);
        lg += w * lw;
        if (tid == 0) s_w[s] = w;
    }
    __syncthreads();

    const float inv_l = 1.0f / lg;
    float v0 = 0.0f, v1 = 0.0f;
    for (int s = 0; s < S; ++s) {
        const float* ap = acc_ws + (((size_t)b * S + s) * CC + c) * DD;
        const float w = s_w[s];
        v0 = fmaf(w, ap[tid], v0);
        v1 = fmaf(w, ap[tid + 256], v1);
    }
    v0 *= inv_l;
    v1 *= inv_l;

    v_out[(size_t)bc * DD + tid]       = v0;
    v_out[(size_t)bc * DD + tid + 256] = v1;

    float part = v0 * lin_w[tid] + v1 * lin_w[tid + 256];
#pragma unroll
    for (int off = 1; off < 64; off <<= 1) part += __shfl_xor(part, off, 64);
    if ((tid & 63) == 0) s_red[tid >> 6] = part;
    __syncthreads();
    if (tid == 0) {
        const float dot = s_red[0] + s_red[1] + s_red[2] + s_red[3] + lin_b[0];
        const float p = tanhf(dot);
        s_p = p;
        p_out[bc] = p;
    }
    __syncthreads();
    const float p = s_p;
    r_out[(size_t)bc * DD + tid]       = p * v0;
    r_out[(size_t)bc * DD + tid + 256] = p * v1;
}

extern "C" void kernel_launch(void* const* d_in, const int* in_sizes, int n_in,
                              void* d_out, int out_size, void* d_ws, size_t ws_size,
                              hipStream_t stream) {
    const float* x   = (const float*)d_in[0];
    const float* Wa  = (const float*)d_in[1];
    const float* lw  = (const float*)d_in[2];
    const float* lb  = (const float*)d_in[3];

    float* out   = (float*)d_out;
    float* p_out = out;                       // (B, C)
    float* v_out = out + BB * CC;             // (B, C, D)
    float* r_out = v_out + BB * CC * DD;      // (B, C, D)

    // choose segment count to fit workspace: need B*S*C*(D+2) floats
    int S = 32;
    while (S > 1 && (size_t)BB * S * CC * (DD + 2) * sizeof(float) > ws_size) S >>= 1;
    const int rows_per_seg = NN / S;

    float* acc_ws = (float*)d_ws;                        // B*S*C*D
    float* ml_ws  = acc_ws + (size_t)BB * S * CC * DD;   // B*S*C*2

    capsule_pass1<<<dim3(BB * S), dim3(256), 0, stream>>>(x, Wa, acc_ws, ml_ws, S, rows_per_seg);
    capsule_pass2<<<dim3(BB * CC), dim3(256), 0, stream>>>(acc_ws, ml_ws, lw, lb,
                                                           p_out, v_out, r_out, S);
}

// Round 4
// 66.843 us; speedup vs baseline: 1.0124x; 1.0124x over previous
//
#include <hip/hip_runtime.h>
#include <math.h>

#define BB 32
#define NN 4096
#define DD 512
#define CC 5

// DPP-add step: v += dpp_permuted(v). bound_ctrl=1 -> 0 for lanes w/o source.
#define DPP_ADD(v, ctrl, rmask)                                                 \
    (v) += __int_as_float(__builtin_amdgcn_update_dpp(                          \
        0, __float_as_int(v), (ctrl), (rmask), 0xF, true))

// Canonical CDNA wave64 all-reduce via DPP only (no DS pipe), result made
// wave-uniform via readlane 63. 6 VALU ops + 1 readlane; chains from
// independent (row,capsule) pairs interleave for ILP.
static __device__ __forceinline__ float wave_allreduce_add(float v)
{
    DPP_ADD(v, 0x111, 0xF);   // row_shr:1
    DPP_ADD(v, 0x112, 0xF);   // row_shr:2
    DPP_ADD(v, 0x114, 0xF);   // row_shr:4
    DPP_ADD(v, 0x118, 0xF);   // row_shr:8
    DPP_ADD(v, 0x142, 0xA);   // row_bcast:15 -> rows 1,3
    DPP_ADD(v, 0x143, 0xC);   // row_bcast:31 -> rows 2,3
    return __int_as_float(__builtin_amdgcn_readlane(__float_as_int(v), 63));
}

// Pass 1: stream x once. Block = (b, segment). 4 waves; each wave owns a
// contiguous 1/4 of the segment rows and processes them in BATCHES OF 4 with
// one softmax max-check/rescale per batch (amortized online softmax).
__global__ __launch_bounds__(256, 3)
void capsule_pass1(const float* __restrict__ x, const float* __restrict__ Wa,
                   float* __restrict__ acc_ws, float* __restrict__ ml_ws,
                   int S, int rows_per_seg)
{
    const int blk  = blockIdx.x;
    const int b    = blk / S;
    const int seg  = blk % S;
    const int tid  = threadIdx.x;
    const int lane = tid & 63;
    const int wid  = tid >> 6;   // 0..3

    // lane owns d in [d0, d0+4) and [d1, d1+4)
    const int d0 = lane * 4;
    const int d1 = 256 + lane * 4;

    // W_alpha fragments: 20 contiguous floats per half (4 d's x 5 c's).
    float wal[20], wah[20];
    {
        const float4* pl = reinterpret_cast<const float4*>(Wa + d0 * CC);
        const float4* ph = reinterpret_cast<const float4*>(Wa + d1 * CC);
#pragma unroll
        for (int q = 0; q < 5; ++q) {
            float4 a = pl[q];
            wal[q * 4 + 0] = a.x; wal[q * 4 + 1] = a.y;
            wal[q * 4 + 2] = a.z; wal[q * 4 + 3] = a.w;
            float4 b4 = ph[q];
            wah[q * 4 + 0] = b4.x; wah[q * 4 + 1] = b4.y;
            wah[q * 4 + 2] = b4.z; wah[q * 4 + 3] = b4.w;
        }
    }

    float acc[CC][8];
    float m[CC], l[CC];   // wave-uniform values (lane-uniform VGPR)
#pragma unroll
    for (int c = 0; c < CC; ++c) {
        m[c] = -INFINITY;
        l[c] = 0.0f;
#pragma unroll
        for (int j = 0; j < 8; ++j) acc[c][j] = 0.0f;
    }

    const float* xseg = x + ((size_t)b * NN + (size_t)seg * rows_per_seg) * DD;

    const int rpw   = rows_per_seg >> 2;        // rows per wave (contiguous)
    const int rbeg  = wid * rpw;
    const int rend  = rbeg + rpw;

    for (int i0 = rbeg; i0 < rend; i0 += 4) {
        // ---- load 4 rows (8x dwordx4 issued together) ----
        float4 xa[4], xb[4];
#pragma unroll
        for (int r = 0; r < 4; ++r) {
            const float* xr = xseg + (size_t)(i0 + r) * DD;
            xa[r] = *reinterpret_cast<const float4*>(xr + d0);
            xb[r] = *reinterpret_cast<const float4*>(xr + d1);
        }

        // ---- e partials: 20 independent dots ----
        float ep[4][CC];
#pragma unroll
        for (int r = 0; r < 4; ++r) {
            const float xv[8] = {xa[r].x, xa[r].y, xa[r].z, xa[r].w,
                                 xb[r].x, xb[r].y, xb[r].z, xb[r].w};
#pragma unroll
            for (int c = 0; c < CC; ++c) {
                float s = 0.0f;
#pragma unroll
                for (int j = 0; j < 4; ++j) s = fmaf(xv[j], wal[j * CC + c], s);
#pragma unroll
                for (int j = 0; j < 4; ++j) s = fmaf(xv[4 + j], wah[j * CC + c], s);
                ep[r][c] = s;
            }
        }

        // ---- 20 interleaved DPP reduce chains -> wave-uniform e ----
        float e[4][CC];
#pragma unroll
        for (int r = 0; r < 4; ++r)
#pragma unroll
            for (int c = 0; c < CC; ++c)
                e[r][c] = wave_allreduce_add(ep[r][c]);

        // ---- batch max + single rescale check ----
        float mb[CC];
#pragma unroll
        for (int c = 0; c < CC; ++c)
            mb[c] = fmaxf(fmaxf(e[0][c], e[1][c]), fmaxf(e[2][c], e[3][c]));

        bool raise = false;
#pragma unroll
        for (int c = 0; c < CC; ++c) raise = raise || (mb[c] > m[c]);

        if (__ballot(raise) != 0ull) {   // wave-uniform scalar branch
#pragma unroll
            for (int c = 0; c < CC; ++c) {
                const float mn = fmaxf(m[c], mb[c]);
                const float sc = __expf(m[c] - mn);   // 0 when m == -inf
                l[c] *= sc;
#pragma unroll
                for (int j = 0; j < 8; ++j) acc[c][j] *= sc;
                m[c] = mn;
            }
        }

        // ---- weighted accumulation (p uniform per (r,c)) ----
#pragma unroll
        for (int r = 0; r < 4; ++r) {
            const float xv[8] = {xa[r].x, xa[r].y, xa[r].z, xa[r].w,
                                 xb[r].x, xb[r].y, xb[r].z, xb[r].w};
#pragma unroll
            for (int c = 0; c < CC; ++c) {
                const float p = __expf(e[r][c] - m[c]);
                l[c] += p;
#pragma unroll
                for (int j = 0; j < 8; ++j) acc[c][j] = fmaf(p, xv[j], acc[c][j]);
            }
        }
    }

    // ---- combine the 4 waves ----
    __shared__ float s_ml[4][CC][2];
    __shared__ float s_acc[CC][DD];   // 10 KB

    if (lane == 0) {
#pragma unroll
        for (int c = 0; c < CC; ++c) {
            s_ml[wid][c][0] = m[c];
            s_ml[wid][c][1] = l[c];
        }
    }
    __syncthreads();

    float mb2[CC], lb2[CC], cw[CC];
#pragma unroll
    for (int c = 0; c < CC; ++c) {
        float mm = s_ml[0][c][0];
#pragma unroll
        for (int w = 1; w < 4; ++w) mm = fmaxf(mm, s_ml[w][c][0]);
        mb2[c] = mm;
        float ll = 0.0f;
#pragma unroll
        for (int w = 0; w < 4; ++w) ll += __expf(s_ml[w][c][0] - mm) * s_ml[w][c][1];
        lb2[c] = ll;
        cw[c] = __expf(s_ml[wid][c][0] - mm);
    }

    // waves deposit (rescaled) accumulators into LDS sequentially
    for (int w = 0; w < 4; ++w) {
        if (wid == w) {
#pragma unroll
            for (int c = 0; c < CC; ++c) {
#pragma unroll
                for (int j = 0; j < 8; ++j) {
                    const int d = (j < 4) ? (d0 + j) : (d1 + j - 4);
                    const float v = acc[c][j] * cw[c];
                    if (w == 0) s_acc[c][d] = v;
                    else        s_acc[c][d] += v;
                }
            }
        }
        __syncthreads();
    }

    // write block partials to workspace (float4)
    float4* accp = reinterpret_cast<float4*>(acc_ws + (size_t)blk * CC * DD);
    const float4* sa = reinterpret_cast<const float4*>(&s_acc[0][0]);
    for (int idx = tid; idx < CC * DD / 4; idx += 256) accp[idx] = sa[idx];
    if (tid < CC) {
        ml_ws[((size_t)blk * CC + tid) * 2 + 0] = mb2[tid];
        ml_ws[((size_t)blk * CC + tid) * 2 + 1] = lb2[tid];
    }
}

// Pass 2: one block per (b,c). Combine S segment partials, normalize,
// epilogue p = tanh(v.w + b), r = p*v, write all three outputs.
__global__ __launch_bounds__(256)
void capsule_pass2(const float* __restrict__ acc_ws, const float* __restrict__ ml_ws,
                   const float* __restrict__ lin_w, const float* __restrict__ lin_b,
                   float* __restrict__ p_out, float* __restrict__ v_out,
                   float* __restrict__ r_out, int S)
{
    const int bc  = blockIdx.x;          // 0..B*C-1
    const int b   = bc / CC;
    const int c   = bc % CC;
    const int tid = threadIdx.x;

    __shared__ float s_w[64];
    __shared__ float s_red[4];
    __shared__ float s_p;

    float mg = -INFINITY;
    for (int s = 0; s < S; ++s)
        mg = fmaxf(mg, ml_ws[(((size_t)b * S + s) * CC + c) * 2]);
    float lg = 0.0f;
    for (int s = 0; s < S; ++s) {
        const float mw = ml_ws[(((size_t)b * S + s) * CC + c) * 2];
        const float lw = ml_ws[(((size_t)b * S + s) * CC + c) * 2 + 1];
        const float w  = __expf(mw - mg);
        lg += w * lw;
        if (tid == 0) s_w[s] = w;
    }
    __syncthreads();

    const float inv_l = 1.0f / lg;
    float v0 = 0.0f, v1 = 0.0f;
    for (int s = 0; s < S; ++s) {
        const float* ap = acc_ws + (((size_t)b * S + s) * CC + c) * DD;
        const float w = s_w[s];
        v0 = fmaf(w, ap[tid], v0);
        v1 = fmaf(w, ap[tid + 256], v1);
    }
    v0 *= inv_l;
    v1 *= inv_l;

    v_out[(size_t)bc * DD + tid]       = v0;
    v_out[(size_t)bc * DD + tid + 256] = v1;

    float part = v0 * lin_w[tid] + v1 * lin_w[tid + 256];
#pragma unroll
    for (int off = 1; off < 64; off <<= 1) part += __shfl_xor(part, off, 64);
    if ((tid & 63) == 0) s_red[tid >> 6] = part;
    __syncthreads();
    if (tid == 0) {
        const float dot = s_red[0] + s_red[1] + s_red[2] + s_red[3] + lin_b[0];
        const float p = tanhf(dot);
        s_p = p;
        p_out[bc] = p;
    }
    __syncthreads();
    const float p = s_p;
    r_out[(size_t)bc * DD + tid]       = p * v0;
    r_out[(size_t)bc * DD + tid + 256] = p * v1;
}

extern "C" void kernel_launch(void* const* d_in, const int* in_sizes, int n_in,
                              void* d_out, int out_size, void* d_ws, size_t ws_size,
                              hipStream_t stream) {
    const float* x   = (const float*)d_in[0];
    const float* Wa  = (const float*)d_in[1];
    const float* lw  = (const float*)d_in[2];
    const float* lb  = (const float*)d_in[3];

    float* out   = (float*)d_out;
    float* p_out = out;                       // (B, C)
    float* v_out = out + BB * CC;             // (B, C, D)
    float* r_out = v_out + BB * CC * DD;      // (B, C, D)

    // choose segment count to fit workspace: need B*S*C*(D+2) floats
    int S = 32;
    while (S > 1 && (size_t)BB * S * CC * (DD + 2) * sizeof(float) > ws_size) S >>= 1;
    const int rows_per_seg = NN / S;

    float* acc_ws = (float*)d_ws;                        // B*S*C*D
    float* ml_ws  = acc_ws + (size_t)BB * S * CC * DD;   // B*S*C*2

    capsule_pass1<<<dim3(BB * S), dim3(256), 0, stream>>>(x, Wa, acc_ws, ml_ws, S, rows_per_seg);
    capsule_pass2<<<dim3(BB * CC), dim3(256), 0, stream>>>(acc_ws, ml_ws, lw, lb,
                                                           p_out, v_out, r_out, S);
}

// Round 5
// 62.364 us; speedup vs baseline: 1.0851x; 1.0718x over previous
//
#include <hip/hip_runtime.h>
#include <math.h>

#define BB 32
#define NN 4096
#define DD 512
#define CC 5
#define SSEG 24   // 32*24 = 768 blocks = exactly 3 resident blocks/CU -> no tail

// DPP-add step: v += dpp_permuted(v). bound_ctrl=1 -> 0 for lanes w/o source.
#define DPP_ADD(v, ctrl, rmask)                                                 \
    (v) += __int_as_float(__builtin_amdgcn_update_dpp(                          \
        0, __float_as_int(v), (ctrl), (rmask), 0xF, true))

// Canonical CDNA wave64 all-reduce via DPP only (no DS pipe), result made
// wave-uniform via readlane 63.
static __device__ __forceinline__ float wave_allreduce_add(float v)
{
    DPP_ADD(v, 0x111, 0xF);   // row_shr:1
    DPP_ADD(v, 0x112, 0xF);   // row_shr:2
    DPP_ADD(v, 0x114, 0xF);   // row_shr:4
    DPP_ADD(v, 0x118, 0xF);   // row_shr:8
    DPP_ADD(v, 0x142, 0xA);   // row_bcast:15 -> rows 1,3
    DPP_ADD(v, 0x143, 0xC);   // row_bcast:31 -> rows 2,3
    return __int_as_float(__builtin_amdgcn_readlane(__float_as_int(v), 63));
}

// Pass 1: stream x once. Block = (b, segment). 4 waves; each wave owns a
// contiguous slice of the segment rows, processed in batches of 4 with one
// amortized softmax max-check/rescale per batch, plus a <=3-row remainder.
__global__ __launch_bounds__(256, 3)
void capsule_pass1(const float* __restrict__ x, const float* __restrict__ Wa,
                   float* __restrict__ acc_ws, float* __restrict__ ml_ws)
{
    const int blk  = blockIdx.x;
    const int b    = blk / SSEG;
    const int seg  = blk % SSEG;
    const int tid  = threadIdx.x;
    const int lane = tid & 63;
    const int wid  = tid >> 6;   // 0..3

    // lane owns d in [d0, d0+4) and [d1, d1+4)
    const int d0 = lane * 4;
    const int d1 = 256 + lane * 4;

    // W_alpha fragments: 20 contiguous floats per half (4 d's x 5 c's).
    float wal[20], wah[20];
    {
        const float4* pl = reinterpret_cast<const float4*>(Wa + d0 * CC);
        const float4* ph = reinterpret_cast<const float4*>(Wa + d1 * CC);
#pragma unroll
        for (int q = 0; q < 5; ++q) {
            float4 a = pl[q];
            wal[q * 4 + 0] = a.x; wal[q * 4 + 1] = a.y;
            wal[q * 4 + 2] = a.z; wal[q * 4 + 3] = a.w;
            float4 b4 = ph[q];
            wah[q * 4 + 0] = b4.x; wah[q * 4 + 1] = b4.y;
            wah[q * 4 + 2] = b4.z; wah[q * 4 + 3] = b4.w;
        }
    }

    float acc[CC][8];
    float m[CC], l[CC];   // wave-uniform values
#pragma unroll
    for (int c = 0; c < CC; ++c) {
        m[c] = -INFINITY;
        l[c] = 0.0f;
#pragma unroll
        for (int j = 0; j < 8; ++j) acc[c][j] = 0.0f;
    }

    // segment rows [rs, re), uneven split via integer division
    const int rs = (seg * NN) / SSEG;
    const int re = ((seg + 1) * NN) / SSEG;
    const int nrows = re - rs;
    // wave's contiguous slice
    const int ws_ = rs + (wid * nrows) / 4;
    const int we_ = rs + ((wid + 1) * nrows) / 4;

    const float* xb_ = x + (size_t)b * NN * DD;

    int i0 = ws_;
    for (; i0 + 4 <= we_; i0 += 4) {
        // ---- load 4 rows ----
        float4 xa[4], xb[4];
#pragma unroll
        for (int r = 0; r < 4; ++r) {
            const float* xr = xb_ + (size_t)(i0 + r) * DD;
            xa[r] = *reinterpret_cast<const float4*>(xr + d0);
            xb[r] = *reinterpret_cast<const float4*>(xr + d1);
        }

        // ---- e partials: 20 independent dots ----
        float ep[4][CC];
#pragma unroll
        for (int r = 0; r < 4; ++r) {
            const float xv[8] = {xa[r].x, xa[r].y, xa[r].z, xa[r].w,
                                 xb[r].x, xb[r].y, xb[r].z, xb[r].w};
#pragma unroll
            for (int c = 0; c < CC; ++c) {
                float s = 0.0f;
#pragma unroll
                for (int j = 0; j < 4; ++j) s = fmaf(xv[j], wal[j * CC + c], s);
#pragma unroll
                for (int j = 0; j < 4; ++j) s = fmaf(xv[4 + j], wah[j * CC + c], s);
                ep[r][c] = s;
            }
        }

        // ---- 20 interleaved DPP reduce chains -> wave-uniform e ----
        float e[4][CC];
#pragma unroll
        for (int r = 0; r < 4; ++r)
#pragma unroll
            for (int c = 0; c < CC; ++c)
                e[r][c] = wave_allreduce_add(ep[r][c]);

        // ---- batch max + single rescale check ----
        float mb[CC];
#pragma unroll
        for (int c = 0; c < CC; ++c)
            mb[c] = fmaxf(fmaxf(e[0][c], e[1][c]), fmaxf(e[2][c], e[3][c]));

        bool raise = false;
#pragma unroll
        for (int c = 0; c < CC; ++c) raise = raise || (mb[c] > m[c]);

        if (__ballot(raise) != 0ull) {   // wave-uniform branch
#pragma unroll
            for (int c = 0; c < CC; ++c) {
                const float mn = fmaxf(m[c], mb[c]);
                const float sc = __expf(m[c] - mn);   // 0 when m == -inf
                l[c] *= sc;
#pragma unroll
                for (int j = 0; j < 8; ++j) acc[c][j] *= sc;
                m[c] = mn;
            }
        }

        // ---- weighted accumulation ----
#pragma unroll
        for (int r = 0; r < 4; ++r) {
            const float xv[8] = {xa[r].x, xa[r].y, xa[r].z, xa[r].w,
                                 xb[r].x, xb[r].y, xb[r].z, xb[r].w};
#pragma unroll
            for (int c = 0; c < CC; ++c) {
                const float p = __expf(e[r][c] - m[c]);
                l[c] += p;
#pragma unroll
                for (int j = 0; j < 8; ++j) acc[c][j] = fmaf(p, xv[j], acc[c][j]);
            }
        }
    }

    // ---- remainder rows (<=3), single-row online update ----
    for (; i0 < we_; ++i0) {
        const float* xr = xb_ + (size_t)i0 * DD;
        const float4 xa = *reinterpret_cast<const float4*>(xr + d0);
        const float4 xb4 = *reinterpret_cast<const float4*>(xr + d1);
        const float xv[8] = {xa.x, xa.y, xa.z, xa.w, xb4.x, xb4.y, xb4.z, xb4.w};

        float e[CC];
#pragma unroll
        for (int c = 0; c < CC; ++c) {
            float s = 0.0f;
#pragma unroll
            for (int j = 0; j < 4; ++j) s = fmaf(xv[j], wal[j * CC + c], s);
#pragma unroll
            for (int j = 0; j < 4; ++j) s = fmaf(xv[4 + j], wah[j * CC + c], s);
            e[c] = wave_allreduce_add(s);
        }
#pragma unroll
        for (int c = 0; c < CC; ++c) {
            if (e[c] > m[c]) {
                const float sc = __expf(m[c] - e[c]);
                l[c] = l[c] * sc + 1.0f;
#pragma unroll
                for (int j = 0; j < 8; ++j) acc[c][j] = fmaf(acc[c][j], sc, xv[j]);
                m[c] = e[c];
            } else {
                const float p = __expf(e[c] - m[c]);
                l[c] += p;
#pragma unroll
                for (int j = 0; j < 8; ++j) acc[c][j] = fmaf(p, xv[j], acc[c][j]);
            }
        }
    }

    // ---- combine the 4 waves ----
    __shared__ float s_ml[4][CC][2];
    __shared__ float s_acc[CC][DD];   // 10 KB

    if (lane == 0) {
#pragma unroll
        for (int c = 0; c < CC; ++c) {
            s_ml[wid][c][0] = m[c];
            s_ml[wid][c][1] = l[c];
        }
    }
    __syncthreads();

    float mb2[CC], lb2[CC], cw[CC];
#pragma unroll
    for (int c = 0; c < CC; ++c) {
        float mm = s_ml[0][c][0];
#pragma unroll
        for (int w = 1; w < 4; ++w) mm = fmaxf(mm, s_ml[w][c][0]);
        mb2[c] = mm;
        float ll = 0.0f;
#pragma unroll
        for (int w = 0; w < 4; ++w) ll += __expf(s_ml[w][c][0] - mm) * s_ml[w][c][1];
        lb2[c] = ll;
        cw[c] = __expf(s_ml[wid][c][0] - mm);
    }

    // waves deposit (rescaled) accumulators into LDS sequentially
    for (int w = 0; w < 4; ++w) {
        if (wid == w) {
#pragma unroll
            for (int c = 0; c < CC; ++c) {
#pragma unroll
                for (int j = 0; j < 8; ++j) {
                    const int d = (j < 4) ? (d0 + j) : (d1 + j - 4);
                    const float v = acc[c][j] * cw[c];
                    if (w == 0) s_acc[c][d] = v;
                    else        s_acc[c][d] += v;
                }
            }
        }
        __syncthreads();
    }

    // write block partials to workspace (float4)
    float4* accp = reinterpret_cast<float4*>(acc_ws + (size_t)blk * CC * DD);
    const float4* sa = reinterpret_cast<const float4*>(&s_acc[0][0]);
    for (int idx = tid; idx < CC * DD / 4; idx += 256) accp[idx] = sa[idx];
    if (tid < CC) {
        ml_ws[((size_t)blk * CC + tid) * 2 + 0] = mb2[tid];
        ml_ws[((size_t)blk * CC + tid) * 2 + 1] = lb2[tid];
    }
}

// Pass 2: one block per (b,c). Combine SSEG segment partials, normalize,
// epilogue p = tanh(v.w + b), r = p*v, write all three outputs.
__global__ __launch_bounds__(256)
void capsule_pass2(const float* __restrict__ acc_ws, const float* __restrict__ ml_ws,
                   const float* __restrict__ lin_w, const float* __restrict__ lin_b,
                   float* __restrict__ p_out, float* __restrict__ v_out,
                   float* __restrict__ r_out)
{
    const int bc  = blockIdx.x;          // 0..B*C-1
    const int b   = bc / CC;
    const int c   = bc % CC;
    const int tid = threadIdx.x;

    __shared__ float s_w[SSEG];
    __shared__ float s_red[4];
    __shared__ float s_p;

    float mg = -INFINITY;
    for (int s = 0; s < SSEG; ++s)
        mg = fmaxf(mg, ml_ws[(((size_t)b * SSEG + s) * CC + c) * 2]);
    float lg = 0.0f;
    for (int s = 0; s < SSEG; ++s) {
        const float mw = ml_ws[(((size_t)b * SSEG + s) * CC + c) * 2];
        const float lw = ml_ws[(((size_t)b * SSEG + s) * CC + c) * 2 + 1];
        const float w  = __expf(mw - mg);
        lg += w * lw;
        if (tid == 0) s_w[s] = w;
    }
    __syncthreads();

    const float inv_l = 1.0f / lg;
    float v0 = 0.0f, v1 = 0.0f;
    for (int s = 0; s < SSEG; ++s) {
        const float* ap = acc_ws + (((size_t)b * SSEG + s) * CC + c) * DD;
        const float w = s_w[s];
        v0 = fmaf(w, ap[tid], v0);
        v1 = fmaf(w, ap[tid + 256], v1);
    }
    v0 *= inv_l;
    v1 *= inv_l;

    v_out[(size_t)bc * DD + tid]       = v0;
    v_out[(size_t)bc * DD + tid + 256] = v1;

    float part = v0 * lin_w[tid] + v1 * lin_w[tid + 256];
#pragma unroll
    for (int off = 1; off < 64; off <<= 1) part += __shfl_xor(part, off, 64);
    if ((tid & 63) == 0) s_red[tid >> 6] = part;
    __syncthreads();
    if (tid == 0) {
        const float dot = s_red[0] + s_red[1] + s_red[2] + s_red[3] + lin_b[0];
        const float p = tanhf(dot);
        s_p = p;
        p_out[bc] = p;
    }
    __syncthreads();
    const float p = s_p;
    r_out[(size_t)bc * DD + tid]       = p * v0;
    r_out[(size_t)bc * DD + tid + 256] = p * v1;
}

extern "C" void kernel_launch(void* const* d_in, const int* in_sizes, int n_in,
                              void* d_out, int out_size, void* d_ws, size_t ws_size,
                              hipStream_t stream) {
    const float* x   = (const float*)d_in[0];
    const float* Wa  = (const float*)d_in[1];
    const float* lw  = (const float*)d_in[2];
    const float* lb  = (const float*)d_in[3];

    float* out   = (float*)d_out;
    float* p_out = out;                       // (B, C)
    float* v_out = out + BB * CC;             // (B, C, D)
    float* r_out = v_out + BB * CC * DD;      // (B, C, D)

    float* acc_ws = (float*)d_ws;                           // B*SSEG*C*D
    float* ml_ws  = acc_ws + (size_t)BB * SSEG * CC * DD;   // B*SSEG*C*2

    capsule_pass1<<<dim3(BB * SSEG), dim3(256), 0, stream>>>(x, Wa, acc_ws, ml_ws);
    capsule_pass2<<<dim3(BB * CC), dim3(256), 0, stream>>>(acc_ws, ml_ws, lw, lb,
                                                           p_out, v_out, r_out);
}